// Round 9
// baseline (74.854 us; speedup 1.0000x reference)
//
#include <hip/hip_runtime.h>
#include <math.h>

#define N      128
#define NS     16
#define NC     4
#define NT     4
#define NPIX   (N * N)       // 16384
#define NJC    (N * NC)      // 512 columns (j*4+c)

typedef __attribute__((ext_vector_type(8))) short bf16x8;   // 8 bf16 = 4 VGPR
typedef __attribute__((ext_vector_type(4))) float f32x4;

// float -> bf16 bits, round-to-nearest-even
__device__ __forceinline__ short f2bf(float f) {
    union { float f; unsigned int u; } v; v.f = f;
    unsigned int r = (v.u + 0x7fffu + ((v.u >> 16) & 1u)) >> 16;
    return (short)r;
}

// cis(2*pi*rev) via hardware v_sin/v_cos (input: revolutions, fract-reduced).
// R1 vs R2 produced bit-identical output -> hw semantics == libm here.
__device__ __forceinline__ void cis_rev(float rev, float& c, float& s) {
    float f = rev - floorf(rev);          // [0,1)
    s = __builtin_amdgcn_sinf(f);
    c = __builtin_amdgcn_cosf(f);
}

// prep v2: thread = (t, jc, i-chunk of 8). One coalesced 16B bf16x8 store.
// Pb[t][jc=j*4+c][i] = bf16(csm[c,i,j] * im_t[i,j]). Block 0 zeroes out.
__global__ __launch_bounds__(256) void prep_kernel(
    const float* __restrict__ x, const float* __restrict__ csm,
    const float* __restrict__ flow, short* __restrict__ Pb,
    float* __restrict__ out, int out_size)
{
    int wIdx = blockIdx.x * 256 + threadIdx.x;   // 0 .. 32767
    int i0 = (wIdx & 15) * 8;
    int jc = (wIdx >> 4) & (NJC - 1);
    int t  = wIdx >> 13;
    int j  = jc >> 2, c = jc & 3;

    bf16x8 v8;
#pragma unroll
    for (int u = 0; u < 8; ++u) {
        int i = i0 + u;
        int p = i * N + j;
        float f0 = flow[(p * 2 + 0) * NT + t];
        float f1 = flow[(p * 2 + 1) * NT + t];
        int si = min(max((int)rintf((float)i + f0), 0), N - 1);
        int sj = min(max((int)rintf((float)j + f1), 0), N - 1);
        float im = x[si * N + sj];
        v8[u] = f2bf(csm[c * NPIX + p] * im);
    }
    *(bf16x8*)(Pb + ((size_t)t * NJC + jc) * N + i0) = v8;

    if (blockIdx.x == 0) {
        for (int k = threadIdx.x; k < out_size; k += 256) out[k] = 0.0f;
    }
}

// MFMA NDFT v2: no LDS. S[m,jc] = sum_i Ex[m,i]*P[i,jc] via 16x16x32 bf16
// MFMA (Exr, Exi chains); epilogue applies per-lane Ey ROTORS (j advances 4
// per tile -> one cmul per C-reg per tile) and reduces.
// Grid 512: b -> mtile = b>>2 (16 m), qh = b&3 (128-jc quarter). Wave = t.
__global__ __launch_bounds__(256) void mfma2_kernel(
    const float* __restrict__ traj, const short* __restrict__ Pb,
    float* __restrict__ out, int out_size)
{
    int b     = blockIdx.x;
    int mtile = b >> 2;            // 0..127
    int qh    = b & 3;             // jc quarter
    int tid   = threadIdx.x;
    int lane  = tid & 63;
    int t     = tid >> 6;          // wave = motion state
    int quad  = lane >> 4;
    int l15   = lane & 15;

    // ---- A fragments: Ex for m = mtile*16 + l15.
    // A layout: A[m = lane&15][k = quad*8 + e], k-step s adds s*32.
    int m  = mtile * 16 + l15;
    int sp = m >> 7, r = m & (N - 1);
    float kx = traj[((sp * N + r) * NT + t) * 2 + 0];

    bf16x8 ar[4], ai[4];
    {
        float stepr, stepi;
        cis_rev(-kx, stepr, stepi);
#pragma unroll
        for (int s = 0; s < 4; ++s) {
            float er, ei;
            cis_rev(-kx * (float)(s * 32 + quad * 8 - 64), er, ei);
#pragma unroll
            for (int e = 0; e < 8; ++e) {
                ar[s][e] = f2bf(er);
                ai[s][e] = f2bf(ei);
                float nr = er * stepr - ei * stepi;
                float ni = fmaf(er, stepi, ei * stepr);
                er = nr; ei = ni;
            }
        }
    }

    // ---- Ey rotors, one per C-reg (mrel = quad*4 + reg).
    // Lane's j at tile nt: j = qh*32 + nt*4 + (l15>>2); step per tile = 4.
    int jlane = l15 >> 2;
    float eyr[4], eyi[4], esr[4], esi[4];
#pragma unroll
    for (int reg = 0; reg < 4; ++reg) {
        int me  = mtile * 16 + quad * 4 + reg;
        int spe = me >> 7, re = me & (N - 1);
        float ky = traj[((spe * N + re) * NT + t) * 2 + 1];
        cis_rev(-ky * 4.0f, esr[reg], esi[reg]);
        cis_rev(-ky * (float)(qh * 32 + jlane - 64), eyr[reg], eyi[reg]);
    }

    // ---- Main loop: 8 jc-tiles of 16.
    const short* PbT = Pb + (size_t)t * NJC * N;
    int jcb0 = qh * 128;
    float partial[4] = {0.f, 0.f, 0.f, 0.f};

    bf16x8 bpre[4];
#pragma unroll
    for (int s = 0; s < 4; ++s)
        bpre[s] = *(const bf16x8*)(PbT + (jcb0 + l15) * N + s * 32 + quad * 8);

    for (int nt = 0; nt < 8; ++nt) {
        bf16x8 bcur[4];
#pragma unroll
        for (int s = 0; s < 4; ++s) bcur[s] = bpre[s];
        if (nt + 1 < 8) {
            int jcn = jcb0 + (nt + 1) * 16 + l15;
#pragma unroll
            for (int s = 0; s < 4; ++s)
                bpre[s] = *(const bf16x8*)(PbT + jcn * N + s * 32 + quad * 8);
        }

        f32x4 accR = {0.f, 0.f, 0.f, 0.f};
        f32x4 accI = {0.f, 0.f, 0.f, 0.f};
#pragma unroll
        for (int s = 0; s < 4; ++s) {
            accR = __builtin_amdgcn_mfma_f32_16x16x32_bf16(ar[s], bcur[s], accR, 0, 0, 0);
            accI = __builtin_amdgcn_mfma_f32_16x16x32_bf16(ai[s], bcur[s], accI, 0, 0, 0);
        }

        // C/D: col = l15 (jc_rel), row = quad*4 + reg (mrel).
#pragma unroll
        for (int reg = 0; reg < 4; ++reg) {
            partial[reg] = fmaf(eyr[reg], accR[reg], partial[reg]);
            partial[reg] = fmaf(-eyi[reg], accI[reg], partial[reg]);
            float nr = eyr[reg] * esr[reg] - eyi[reg] * esi[reg];
            float ni = fmaf(eyr[reg], esi[reg], eyi[reg] * esr[reg]);
            eyr[reg] = nr; eyi[reg] = ni;
        }
    }

    // ---- Reduce over the 4 j-subgroups (lane bits 2,3).
#pragma unroll
    for (int reg = 0; reg < 4; ++reg) {
        partial[reg] += __shfl_xor(partial[reg], 4, 64);
        partial[reg] += __shfl_xor(partial[reg], 8, 64);
    }
    if ((lane & 12) == 0) {
        int c = lane & 3;
#pragma unroll
        for (int reg = 0; reg < 4; ++reg) {
            int mm  = mtile * 16 + quad * 4 + reg;
            int sp2 = mm >> 7, r2 = mm & (N - 1);
            int q = (r2 * NS + sp2) * NC + c;   // C-order into [1][128][16][4]
            if (q < out_size) atomicAdd(&out[q], partial[reg]);
        }
    }
}

extern "C" void kernel_launch(void* const* d_in, const int* in_sizes, int n_in,
                              void* d_out, int out_size, void* d_ws, size_t ws_size,
                              hipStream_t stream) {
    const float* x    = (const float*)d_in[0];
    const float* traj = (const float*)d_in[1];
    const float* csm  = (const float*)d_in[2];
    // d_in[3] = dcf (unused by the reference)
    const float* flow = (const float*)d_in[4];
    float* out = (float*)d_out;
    short* Pb  = (short*)d_ws;    // NT*512*128 bf16 = 512 KiB

    prep_kernel<<<dim3(128), dim3(256), 0, stream>>>(x, csm, flow, Pb, out, out_size);
    mfma2_kernel<<<dim3(512), dim3(256), 0, stream>>>(traj, Pb, out, out_size);
}